// Round 17
// baseline (348.513 us; speedup 1.0000x reference)
//
#include <hip/hip_runtime.h>

#define N_NODES 100000
#define N_EDGES 3200000

// CSR sort geometry
#define BSH 8                        // 256 nodes per bucket
#define NB 391                       // ceil(100000/256)
#define G_SRT 512                    // blocks in scatter pass
#define EPB 6256                     // edges per block (mult of 4; 512*6256 >= E)
#define CAPB 9216                    // col/bins entries per bucket (mean 8184, +11 sigma)

typedef __attribute__((ext_vector_type(8))) short bf16x8;
typedef __attribute__((ext_vector_type(4))) float f32x4;

// f32 -> bf16 round-to-nearest-even
__device__ __forceinline__ unsigned short f2bf(float f) {
    unsigned u = __float_as_uint(f);
    u = (u + 0x7FFFu + ((u >> 16) & 1u)) >> 16;
    return (unsigned short)u;
}
__device__ __forceinline__ float bf2f(unsigned short b) {
    return __uint_as_float(((unsigned)b) << 16);
}
__device__ __forceinline__ float bfp_lo(unsigned u) { return __uint_as_float(u << 16); }
__device__ __forceinline__ float bfp_hi(unsigned u) { return __uint_as_float(u & 0xFFFF0000u); }

// ======================= prep: W^T bf16 + bucket cursors =======================

__global__ void k_prep(const float* __restrict__ W1, const float* __restrict__ W2,
                       unsigned short* __restrict__ wt1, unsigned short* __restrict__ wt2,
                       int* __restrict__ gcur) {
    int gid = blockIdx.x * blockDim.x + threadIdx.x;
    int stride = gridDim.x * blockDim.x;
    for (int i = gid; i < 64 * 256; i += stride) {
        int c = i >> 8, k = i & 255;
        wt1[i] = f2bf(W1[k * 64 + c]);
    }
    for (int i = gid; i < 32 * 64; i += stride) {
        int c = i >> 6, k = i & 63;
        wt2[i] = f2bf(W2[k * 32 + c]);
    }
    for (int i = gid; i < NB; i += stride) gcur[i] = i * CAPB;
}

// ======================= CSR build: block multisplit + atomic bucket reservation =======================

__global__ __launch_bounds__(256) void k_scatter_srt(const int* __restrict__ ei,
                                                     int* __restrict__ gcur,
                                                     unsigned* __restrict__ bins, int e) {
    __shared__ unsigned sbuf[EPB];                 // 25 KB staging
    __shared__ int lh[NB], lcur[NB], gdst[NB];
    __shared__ int sA[NB], sBf[NB];
    int b = (int)blockIdx.x, t = (int)threadIdx.x;
    int i0 = b * EPB, i1 = i0 + EPB; if (i1 > e) i1 = e;

    for (int k = t; k < NB; k += 256) lh[k] = 0;
    __syncthreads();
    for (int i = i0 + t * 4; i + 3 < i1; i += 1024) {
        int4 d4 = *(const int4*)(ei + e + i);
        if ((unsigned)d4.x < (unsigned)N_NODES) atomicAdd(&lh[d4.x >> BSH], 1);
        if ((unsigned)d4.y < (unsigned)N_NODES) atomicAdd(&lh[d4.y >> BSH], 1);
        if ((unsigned)d4.z < (unsigned)N_NODES) atomicAdd(&lh[d4.z >> BSH], 1);
        if ((unsigned)d4.w < (unsigned)N_NODES) atomicAdd(&lh[d4.w >> BSH], 1);
    }
    __syncthreads();

    // local inclusive scan over NB buckets (LDS staging offsets)
    int* cur = sA; int* nxt = sBf;
    for (int k = t; k < NB; k += 256) cur[k] = lh[k];
    __syncthreads();
    for (int off = 1; off < NB; off <<= 1) {
        for (int k = t; k < NB; k += 256) nxt[k] = cur[k] + (k >= off ? cur[k - off] : 0);
        __syncthreads();
        int* tmp = cur; cur = nxt; nxt = tmp;
    }
    // reserve global ranges: one atomic per (block, bucket)
    for (int k = t; k < NB; k += 256) {
        lcur[k] = cur[k] - lh[k];
        gdst[k] = lh[k] ? atomicAdd(&gcur[k], lh[k]) : 0;
    }
    __syncthreads();

    // rank + stage into LDS (bucket-sorted within tile)
    for (int i = i0 + t * 4; i + 3 < i1; i += 1024) {
        int4 s4 = *(const int4*)(ei + i);
        int4 d4 = *(const int4*)(ei + e + i);
        int ss[4] = {s4.x, s4.y, s4.z, s4.w};
        int dd[4] = {d4.x, d4.y, d4.z, d4.w};
#pragma unroll
        for (int j = 0; j < 4; ++j) {
            int s = ss[j], d = dd[j];
            if ((unsigned)s >= (unsigned)N_NODES || (unsigned)d >= (unsigned)N_NODES) continue;
            int k = d >> BSH;
            int p = atomicAdd(&lcur[k], 1);
            sbuf[p] = ((unsigned)(d & 255) << 17) | (unsigned)s;
        }
    }
    __syncthreads();

    // contiguous copies into reserved ranges
    int wv = t >> 6, ln = t & 63;
    for (int k = wv; k < NB; k += 4) {
        int cnt = lh[k];
        int src0 = lcur[k] - cnt;
        int dst0 = gdst[k];
        for (int j = ln; j < cnt; j += 64) bins[dst0 + j] = sbuf[src0 + j];
    }
}

__global__ __launch_bounds__(256) void k_bucket(const unsigned* __restrict__ bins,
                                                const int* __restrict__ gcur,
                                                int* __restrict__ rpb, int* __restrict__ rpe,
                                                float* __restrict__ dinv,
                                                int* __restrict__ col, int n) {
    int b = (int)blockIdx.x;
    int t = (int)threadIdx.x;
    int base = b * CAPB;
    int len = gcur[b] - base;
    int nv = len & ~3;
    __shared__ int lcnt[256], lsc[256], lcur[256];
    lcnt[t] = 0;
    __syncthreads();
    for (int i = t * 4; i < nv; i += 1024) {
        uint4 v = *(const uint4*)(bins + base + i);
        atomicAdd(&lcnt[v.x >> 17], 1);
        atomicAdd(&lcnt[v.y >> 17], 1);
        atomicAdd(&lcnt[v.z >> 17], 1);
        atomicAdd(&lcnt[v.w >> 17], 1);
    }
    if (nv + t < len) atomicAdd(&lcnt[bins[base + nv + t] >> 17], 1);
    __syncthreads();
    int c = lcnt[t];
    lsc[t] = c;
    __syncthreads();
    for (int off = 1; off < 256; off <<= 1) {
        int x = (t >= off) ? lsc[t - off] : 0;
        __syncthreads();
        lsc[t] += x;
        __syncthreads();
    }
    int excl = lsc[t] - c;
    int v = (b << BSH) + t;
    if (v < n) {
        rpb[v] = base + excl;
        rpe[v] = base + excl + c;
        dinv[v] = rsqrtf((float)(c + 1));
    }
    lcur[t] = excl;
    __syncthreads();
    for (int i = t * 4; i < nv; i += 1024) {
        uint4 vv = *(const uint4*)(bins + base + i);
        unsigned es[4] = {vv.x, vv.y, vv.z, vv.w};
#pragma unroll
        for (int j = 0; j < 4; ++j) {
            int p = atomicAdd(&lcur[es[j] >> 17], 1);
            col[base + p] = (int)(es[j] & 0x1FFFFu);
        }
    }
    if (nv + t < len) {
        unsigned ent = bins[base + nv + t];
        int p = atomicAdd(&lcur[ent >> 17], 1);
        col[base + p] = (int)(ent & 0x1FFFFu);
    }
}

// ======================= dense MFMA (f32 input): H = (x @ W) * dinv =======================
template <int K, int OUT>
__global__ __launch_bounds__(256) void k_gemm_mfma(const float* __restrict__ x,
                                                   const unsigned short* __restrict__ wt,
                                                   const float* __restrict__ dinv,
                                                   unsigned short* __restrict__ h, int n) {
    constexpr int BM = 64;
    constexpr int BK = 64;
    constexpr int NT = OUT / 16;
    __shared__ unsigned short xs[BM * BK];
    __shared__ unsigned short wsl[OUT * BK];

    int t = (int)threadIdx.x;
    int w = t >> 6;
    int l = t & 63;
    int m0 = blockIdx.x * BM;

    f32x4 acc[NT];
#pragma unroll
    for (int nt = 0; nt < NT; ++nt) acc[nt] = (f32x4){0.f, 0.f, 0.f, 0.f};

    int r = t >> 2, q = t & 3;
    int node_r = m0 + r; if (node_r >= n) node_r = n - 1;

    for (int kb = 0; kb < K; kb += BK) {
        if (kb) __syncthreads();
        const float* xr = x + (long long)node_r * K + kb;
#pragma unroll
        for (int j = 0; j < 2; ++j) {
            int g = q * 2 + j;
            float4 v0 = *(const float4*)(xr + g * 8);
            float4 v1 = *(const float4*)(xr + g * 8 + 4);
            ushort4 lo, hi;
            lo.x = f2bf(v0.x); lo.y = f2bf(v0.y); lo.z = f2bf(v0.z); lo.w = f2bf(v0.w);
            hi.x = f2bf(v1.x); hi.y = f2bf(v1.y); hi.z = f2bf(v1.z); hi.w = f2bf(v1.w);
            int gp = g ^ (r & 7);
            *(ushort4*)&xs[r * BK + gp * 8] = lo;
            *(ushort4*)&xs[r * BK + gp * 8 + 4] = hi;
        }
        for (int f = t; f < OUT * 8; f += 256) {
            int c = f >> 3, g = f & 7;
            uint4 v = *(const uint4*)(wt + (long long)c * K + kb + g * 8);
            int gp = g ^ (c & 7);
            *(uint4*)&wsl[c * BK + gp * 8] = v;
        }
        __syncthreads();
#pragma unroll
        for (int kk = 0; kk < 2; ++kk) {
            int row = w * 16 + (l & 15);
            int gl = kk * 4 + (l >> 4);
            bf16x8 a = *(const bf16x8*)&xs[row * BK + (gl ^ (row & 7)) * 8];
#pragma unroll
            for (int nt = 0; nt < NT; ++nt) {
                int colb = nt * 16 + (l & 15);
                bf16x8 bb = *(const bf16x8*)&wsl[colb * BK + (gl ^ (colb & 7)) * 8];
                acc[nt] = __builtin_amdgcn_mfma_f32_16x16x32_bf16(a, bb, acc[nt], 0, 0, 0);
            }
        }
    }

#pragma unroll
    for (int rg = 0; rg < 4; ++rg) {
        int node = m0 + w * 16 + (l >> 4) * 4 + rg;
        if (node < n) {
            float di = dinv[node];
#pragma unroll
            for (int nt = 0; nt < NT; ++nt)
                h[(long long)node * OUT + nt * 16 + (l & 15)] = f2bf(acc[nt][rg] * di);
        }
    }
}

// ======================= dense MFMA (bf16 input): H = (A @ W) * dinv, K=64 =======================
template <int K, int OUT>
__global__ __launch_bounds__(256) void k_gemm_mfma_b16(const unsigned short* __restrict__ x,
                                                       const unsigned short* __restrict__ wt,
                                                       const float* __restrict__ dinv,
                                                       unsigned short* __restrict__ h, int n) {
    constexpr int BM = 64;
    constexpr int NT = OUT / 16;
    constexpr int GR = K / 8;
    constexpr int SM = GR - 1;
    __shared__ unsigned short xs[BM * K];
    __shared__ unsigned short wsl[OUT * K];

    int t = (int)threadIdx.x;
    int w = t >> 6;
    int l = t & 63;
    int m0 = blockIdx.x * BM;

    f32x4 acc[NT];
#pragma unroll
    for (int nt = 0; nt < NT; ++nt) acc[nt] = (f32x4){0.f, 0.f, 0.f, 0.f};

    constexpr int PER = (BM * GR) / 256;
#pragma unroll
    for (int f = 0; f < PER; ++f) {
        int flat = f * 256 + t;
        int row = flat / GR;
        int g = flat % GR;
        int node = m0 + row; if (node >= n) node = n - 1;
        uint4 v = *(const uint4*)(x + (long long)node * K + g * 8);
        *(uint4*)&xs[row * K + (g ^ (row & SM)) * 8] = v;
    }
    for (int f = t; f < OUT * GR; f += 256) {
        int c = f / GR, g = f % GR;
        uint4 v = *(const uint4*)(wt + (long long)c * K + g * 8);
        *(uint4*)&wsl[c * K + (g ^ (c & SM)) * 8] = v;
    }
    __syncthreads();

#pragma unroll
    for (int kk = 0; kk < K / 32; ++kk) {
        int row = w * 16 + (l & 15);
        int gl = kk * 4 + (l >> 4);
        bf16x8 a = *(const bf16x8*)&xs[row * K + (gl ^ (row & SM)) * 8];
#pragma unroll
        for (int nt = 0; nt < NT; ++nt) {
            int colb = nt * 16 + (l & 15);
            bf16x8 bb = *(const bf16x8*)&wsl[colb * K + (gl ^ (colb & SM)) * 8];
            acc[nt] = __builtin_amdgcn_mfma_f32_16x16x32_bf16(a, bb, acc[nt], 0, 0, 0);
        }
    }

#pragma unroll
    for (int rg = 0; rg < 4; ++rg) {
        int node = m0 + w * 16 + (l >> 4) * 4 + rg;
        if (node < n) {
            float di = dinv[node];
#pragma unroll
            for (int nt = 0; nt < NT; ++nt)
                h[(long long)node * OUT + nt * 16 + (l & 15)] = f2bf(acc[nt][rg] * di);
        }
    }
}

// ======================= gather helper (bf16 rows, f32 acc, 4x/2x/1x MLP) =======================
template <int D>
__device__ __forceinline__ void gather_acc(const unsigned short* __restrict__ hq,
                                           const int* __restrict__ col,
                                           int beg, int end, int eg, float acc[8]) {
    constexpr int LPR = D / 8;
    constexpr int EG = 64 / LPR;
    int i = beg + eg;
    for (; i + 3 * EG < end; i += 4 * EG) {
        int s0 = col[i], s1 = col[i + EG], s2 = col[i + 2 * EG], s3 = col[i + 3 * EG];
        uint4 h0 = *(const uint4*)(hq + (long long)s0 * D);
        uint4 h1 = *(const uint4*)(hq + (long long)s1 * D);
        uint4 h2 = *(const uint4*)(hq + (long long)s2 * D);
        uint4 h3 = *(const uint4*)(hq + (long long)s3 * D);
        acc[0] += bfp_lo(h0.x) + bfp_lo(h1.x) + bfp_lo(h2.x) + bfp_lo(h3.x);
        acc[1] += bfp_hi(h0.x) + bfp_hi(h1.x) + bfp_hi(h2.x) + bfp_hi(h3.x);
        acc[2] += bfp_lo(h0.y) + bfp_lo(h1.y) + bfp_lo(h2.y) + bfp_lo(h3.y);
        acc[3] += bfp_hi(h0.y) + bfp_hi(h1.y) + bfp_hi(h2.y) + bfp_hi(h3.y);
        acc[4] += bfp_lo(h0.z) + bfp_lo(h1.z) + bfp_lo(h2.z) + bfp_lo(h3.z);
        acc[5] += bfp_hi(h0.z) + bfp_hi(h1.z) + bfp_hi(h2.z) + bfp_hi(h3.z);
        acc[6] += bfp_lo(h0.w) + bfp_lo(h1.w) + bfp_lo(h2.w) + bfp_lo(h3.w);
        acc[7] += bfp_hi(h0.w) + bfp_hi(h1.w) + bfp_hi(h2.w) + bfp_hi(h3.w);
    }
    for (; i + EG < end; i += 2 * EG) {
        int s0 = col[i], s1 = col[i + EG];
        uint4 h0 = *(const uint4*)(hq + (long long)s0 * D);
        uint4 h1 = *(const uint4*)(hq + (long long)s1 * D);
        acc[0] += bfp_lo(h0.x) + bfp_lo(h1.x);
        acc[1] += bfp_hi(h0.x) + bfp_hi(h1.x);
        acc[2] += bfp_lo(h0.y) + bfp_lo(h1.y);
        acc[3] += bfp_hi(h0.y) + bfp_hi(h1.y);
        acc[4] += bfp_lo(h0.z) + bfp_lo(h1.z);
        acc[5] += bfp_hi(h0.z) + bfp_hi(h1.z);
        acc[6] += bfp_lo(h0.w) + bfp_lo(h1.w);
        acc[7] += bfp_hi(h0.w) + bfp_hi(h1.w);
    }
    for (; i < end; i += EG) {
        int s = col[i];
        uint4 hv = *(const uint4*)(hq + (long long)s * D);
        acc[0] += bfp_lo(hv.x); acc[1] += bfp_hi(hv.x);
        acc[2] += bfp_lo(hv.y); acc[3] += bfp_hi(hv.y);
        acc[4] += bfp_lo(hv.z); acc[5] += bfp_hi(hv.z);
        acc[6] += bfp_lo(hv.w); acc[7] += bfp_hi(hv.w);
    }
}

// ======================= aggregate (layer 1: D=64, relu -> bf16) =======================
__global__ void k_aggregate64(const unsigned short* __restrict__ h, const int* __restrict__ rpb,
                              const int* __restrict__ rpe, const int* __restrict__ col,
                              const float* __restrict__ dinv, const float* __restrict__ b,
                              unsigned short* __restrict__ out, int n) {
    constexpr int D = 64, LPR = 8;
    int v = (int)((blockIdx.x * blockDim.x + threadIdx.x) >> 6);
    if (v >= n) return;
    int lane = (int)threadIdx.x & 63;
    int eg = lane / LPR;
    int o8 = lane % LPR;
    int beg = rpb[v], end = rpe[v];

    float acc[8];
#pragma unroll
    for (int j = 0; j < 8; ++j) acc[j] = 0.0f;
    gather_acc<D>(h + o8 * 8, col, beg, end, eg, acc);

#pragma unroll
    for (int off = LPR; off < 64; off <<= 1)
#pragma unroll
        for (int j = 0; j < 8; ++j) acc[j] += __shfl_xor(acc[j], off, 64);

    if (lane < LPR) {
        uint4 sv = *(const uint4*)(h + (long long)v * D + o8 * 8);
        float self[8] = {bfp_lo(sv.x), bfp_hi(sv.x), bfp_lo(sv.y), bfp_hi(sv.y),
                         bfp_lo(sv.z), bfp_hi(sv.z), bfp_lo(sv.w), bfp_hi(sv.w)};
        float4 b0 = *(const float4*)(b + o8 * 8);
        float4 b1 = *(const float4*)(b + o8 * 8 + 4);
        float bb[8] = {b0.x, b0.y, b0.z, b0.w, b1.x, b1.y, b1.z, b1.w};
        float di = dinv[v];
        ushort4 t0, t1;
        t0.x = f2bf(fmaxf(di * (acc[0] + self[0]) + bb[0], 0.f));
        t0.y = f2bf(fmaxf(di * (acc[1] + self[1]) + bb[1], 0.f));
        t0.z = f2bf(fmaxf(di * (acc[2] + self[2]) + bb[2], 0.f));
        t0.w = f2bf(fmaxf(di * (acc[3] + self[3]) + bb[3], 0.f));
        t1.x = f2bf(fmaxf(di * (acc[4] + self[4]) + bb[4], 0.f));
        t1.y = f2bf(fmaxf(di * (acc[5] + self[5]) + bb[5], 0.f));
        t1.z = f2bf(fmaxf(di * (acc[6] + self[6]) + bb[6], 0.f));
        t1.w = f2bf(fmaxf(di * (acc[7] + self[7]) + bb[7], 0.f));
        unsigned short* op = out + (long long)v * D + o8 * 8;
        *(ushort4*)op = t0;
        *(ushort4*)(op + 4) = t1;
    }
}

// ======================= fused aggregate+next-GEMM (D in {32,16}, DO = next dim) ===============
// val = relu(dinv*(acc+self)+b); hout[v] = bf16((val @ Wn) * dinv[v])  [DO bf16 per node]
template <int D, int DO>
__global__ void k_agg_fused(const unsigned short* __restrict__ h, const int* __restrict__ rpb,
                            const int* __restrict__ rpe, const int* __restrict__ col,
                            const float* __restrict__ dinv, const float* __restrict__ b,
                            const float* __restrict__ Wn, unsigned short* __restrict__ hout,
                            int n) {
    constexpr int LPR = D / 8;
    __shared__ float wsd[D * DO];
    int t = (int)threadIdx.x;
    for (int i = t; i < D * DO; i += 256) wsd[i] = Wn[i];
    __syncthreads();

    int v = (int)((blockIdx.x * blockDim.x + t) >> 6);
    if (v >= n) return;
    int lane = t & 63;
    int eg = lane / LPR;
    int o8 = lane % LPR;
    int beg = rpb[v], end = rpe[v];

    float acc[8];
#pragma unroll
    for (int j = 0; j < 8; ++j) acc[j] = 0.0f;
    gather_acc<D>(h + o8 * 8, col, beg, end, eg, acc);

#pragma unroll
    for (int off = LPR; off < 64; off <<= 1)
#pragma unroll
        for (int j = 0; j < 8; ++j) acc[j] += __shfl_xor(acc[j], off, 64);

    if (lane < LPR) {
        uint4 sv = *(const uint4*)(h + (long long)v * D + o8 * 8);
        float self[8] = {bfp_lo(sv.x), bfp_hi(sv.x), bfp_lo(sv.y), bfp_hi(sv.y),
                         bfp_lo(sv.z), bfp_hi(sv.z), bfp_lo(sv.w), bfp_hi(sv.w)};
        float4 b0 = *(const float4*)(b + o8 * 8);
        float4 b1 = *(const float4*)(b + o8 * 8 + 4);
        float bb[8] = {b0.x, b0.y, b0.z, b0.w, b1.x, b1.y, b1.z, b1.w};
        float di = dinv[v];
        float val[8];
#pragma unroll
        for (int j = 0; j < 8; ++j)
            val[j] = fmaxf(di * (acc[j] + self[j]) + bb[j], 0.0f);

        // fused next-layer gemm: part[o] = sum_j val[j] * Wn[(o8*8+j)][o]
        float part[DO];
#pragma unroll
        for (int o = 0; o < DO; ++o) part[o] = 0.0f;
#pragma unroll
        for (int j = 0; j < 8; ++j) {
            const float* wr = &wsd[(o8 * 8 + j) * DO];
            float vj = val[j];
#pragma unroll
            for (int o4 = 0; o4 < DO / 4; ++o4) {
                float4 wv = *(const float4*)(wr + o4 * 4);
                part[o4 * 4 + 0] = fmaf(vj, wv.x, part[o4 * 4 + 0]);
                part[o4 * 4 + 1] = fmaf(vj, wv.y, part[o4 * 4 + 1]);
                part[o4 * 4 + 2] = fmaf(vj, wv.z, part[o4 * 4 + 2]);
                part[o4 * 4 + 3] = fmaf(vj, wv.w, part[o4 * 4 + 3]);
            }
        }
#pragma unroll
        for (int off = 1; off < LPR; off <<= 1)
#pragma unroll
            for (int o = 0; o < DO; ++o) part[o] += __shfl_xor(part[o], off, 64);

        if (o8 == 0) {
            unsigned short* op = hout + (long long)v * DO;
#pragma unroll
            for (int o4 = 0; o4 < DO / 4; ++o4) {
                ushort4 w4;
                w4.x = f2bf(part[o4 * 4 + 0] * di);
                w4.y = f2bf(part[o4 * 4 + 1] * di);
                w4.z = f2bf(part[o4 * 4 + 2] * di);
                w4.w = f2bf(part[o4 * 4 + 3] * di);
                *(ushort4*)(op + o4 * 4) = w4;
            }
        }
    }
}

// ======================= final aggregate (D=4, log_softmax -> f32) =======================
__global__ void k_aggregate4(const unsigned short* __restrict__ h, const int* __restrict__ rpb,
                             const int* __restrict__ rpe, const int* __restrict__ col,
                             const float* __restrict__ dinv, const float* __restrict__ b,
                             float* __restrict__ out, int n) {
    int v = (int)((blockIdx.x * blockDim.x + threadIdx.x) >> 6);
    if (v >= n) return;
    int lane = (int)threadIdx.x & 63;
    int beg = rpb[v], end = rpe[v];

    float4 acc = make_float4(0.f, 0.f, 0.f, 0.f);
    for (int i = beg + lane; i < end; i += 64) {
        int s = col[i];
        ushort4 hv = *(const ushort4*)(h + (long long)s * 4);
        acc.x += bf2f(hv.x); acc.y += bf2f(hv.y);
        acc.z += bf2f(hv.z); acc.w += bf2f(hv.w);
    }
#pragma unroll
    for (int off = 1; off < 64; off <<= 1) {
        acc.x += __shfl_xor(acc.x, off, 64);
        acc.y += __shfl_xor(acc.y, off, 64);
        acc.z += __shfl_xor(acc.z, off, 64);
        acc.w += __shfl_xor(acc.w, off, 64);
    }
    if (lane == 0) {
        ushort4 sv = *(const ushort4*)(h + (long long)v * 4);
        float4 bb = *(const float4*)b;
        float di = dinv[v];
        float x0 = di * (acc.x + bf2f(sv.x)) + bb.x;
        float x1 = di * (acc.y + bf2f(sv.y)) + bb.y;
        float x2 = di * (acc.z + bf2f(sv.z)) + bb.z;
        float x3 = di * (acc.w + bf2f(sv.w)) + bb.w;
        float m = fmaxf(fmaxf(x0, x1), fmaxf(x2, x3));
        float s0 = __expf(x0 - m) + __expf(x1 - m) + __expf(x2 - m) + __expf(x3 - m);
        float ls = m + __logf(s0);
        *(float4*)(out + (long long)v * 4) =
            make_float4(x0 - ls, x1 - ls, x2 - ls, x3 - ls);
    }
}

// ======================= launch =======================

extern "C" void kernel_launch(void* const* d_in, const int* in_sizes, int n_in,
                              void* d_out, int out_size, void* d_ws, size_t ws_size,
                              hipStream_t stream) {
    const float* x = (const float*)d_in[0];
    const int* ei = (const int*)d_in[1];  // int32 [2, E]
    const float* W1 = (const float*)d_in[2];
    const float* b1 = (const float*)d_in[3];
    const float* W2 = (const float*)d_in[4];
    const float* b2 = (const float*)d_in[5];
    const float* W3 = (const float*)d_in[6];
    const float* b3 = (const float*)d_in[7];
    const float* W4 = (const float*)d_in[8];
    const float* b4 = (const float*)d_in[9];
    float* out = (float*)d_out;

    const int n = N_NODES;
    const int e = N_EDGES;
    const int B = 256;

    char* ws = (char*)d_ws;
    size_t off = 0;
    auto alloc = [&](size_t bytes) {
        void* p = ws + off;
        off += (bytes + 255) & ~size_t(255);
        return p;
    };
    float* dinv = (float*)alloc((size_t)n * 4);
    int* rpb = (int*)alloc((size_t)n * 4);
    int* rpe = (int*)alloc((size_t)n * 4);
    int* gcur = (int*)alloc((size_t)NB * 4);
    unsigned* bins = (unsigned*)alloc((size_t)NB * CAPB * 4);   // 14.4 MB
    int* col = (int*)alloc((size_t)NB * CAPB * 4);              // 14.4 MB
    unsigned short* H = (unsigned short*)alloc((size_t)n * 64 * 2);   // bf16 (H1/H2/H4)
    unsigned short* A = (unsigned short*)alloc((size_t)n * 64 * 2);   // bf16 (A1/H3)
    unsigned short* wt1 = (unsigned short*)alloc((size_t)64 * 256 * 2);
    unsigned short* wt2 = (unsigned short*)alloc((size_t)32 * 64 * 2);

    // ---- prep (W^T bf16, bucket cursors) + CSR build ----
    k_prep<<<18, B, 0, stream>>>(W1, W2, wt1, wt2, gcur);
    k_scatter_srt<<<G_SRT, B, 0, stream>>>(ei, gcur, bins, e);
    k_bucket<<<NB, B, 0, stream>>>(bins, gcur, rpb, rpe, dinv, col, n);

    const int gblk = (n + 63) / 64;   // BM=64 blocks
    const int ablk = (n + 3) / 4;     // aggregate blocks (4 waves / block)

    // ---- layer 1: 256 -> 64 (MFMA f32-in); aggregate -> A1 bf16 ----
    k_gemm_mfma<256, 64><<<gblk, B, 0, stream>>>(x, wt1, dinv, H, n);
    k_aggregate64<<<ablk, B, 0, stream>>>(H, rpb, rpe, col, dinv, b1, A, n);

    // ---- layer 2: 64 -> 32 (MFMA bf16-in) -> H2; aggregate+fused gemm3 -> H3 ----
    k_gemm_mfma_b16<64, 32><<<gblk, B, 0, stream>>>(A, wt2, dinv, H, n);
    k_agg_fused<32, 16><<<ablk, B, 0, stream>>>(H, rpb, rpe, col, dinv, b2, W3, A, n);

    // ---- layer 3 aggregate + fused gemm4 -> H4 ----
    k_agg_fused<16, 4><<<ablk, B, 0, stream>>>(A, rpb, rpe, col, dinv, b3, W4, H, n);

    // ---- layer 4 aggregate: log_softmax -> out ----
    k_aggregate4<<<ablk, B, 0, stream>>>(H, rpb, rpe, col, dinv, b4, out, n);
}

// Round 18
// 279.105 us; speedup vs baseline: 1.2487x; 1.2487x over previous
//
#include <hip/hip_runtime.h>

#define N_NODES 100000
#define N_EDGES 3200000

// CSR sort geometry
#define BSH 8                        // 256 nodes per bucket
#define NB 391                       // ceil(100000/256)
#define G_SRT 512                    // blocks in scatter pass
#define EPB 6256                     // edges per block (mult of 4; 512*6256 >= E)
#define CAPB 9216                    // col/bins entries per bucket (mean 8184, +11 sigma)

typedef __attribute__((ext_vector_type(8))) short bf16x8;
typedef __attribute__((ext_vector_type(4))) float f32x4;

// f32 -> bf16 round-to-nearest-even
__device__ __forceinline__ unsigned short f2bf(float f) {
    unsigned u = __float_as_uint(f);
    u = (u + 0x7FFFu + ((u >> 16) & 1u)) >> 16;
    return (unsigned short)u;
}
__device__ __forceinline__ float bf2f(unsigned short b) {
    return __uint_as_float(((unsigned)b) << 16);
}
__device__ __forceinline__ float bfp_lo(unsigned u) { return __uint_as_float(u << 16); }
__device__ __forceinline__ float bfp_hi(unsigned u) { return __uint_as_float(u & 0xFFFF0000u); }

// ======================= prep: W^T bf16 + bucket cursors =======================

__global__ void k_prep(const float* __restrict__ W1, const float* __restrict__ W2,
                       const float* __restrict__ W3,
                       unsigned short* __restrict__ wt1, unsigned short* __restrict__ wt2,
                       unsigned short* __restrict__ wt3, int* __restrict__ gcur) {
    int gid = blockIdx.x * blockDim.x + threadIdx.x;
    int stride = gridDim.x * blockDim.x;
    for (int i = gid; i < 64 * 256; i += stride) {
        int c = i >> 8, k = i & 255;
        wt1[i] = f2bf(W1[k * 64 + c]);
    }
    for (int i = gid; i < 32 * 64; i += stride) {
        int c = i >> 6, k = i & 63;
        wt2[i] = f2bf(W2[k * 32 + c]);
    }
    for (int i = gid; i < 16 * 32; i += stride) {
        int c = i >> 5, k = i & 31;
        wt3[i] = f2bf(W3[k * 16 + c]);
    }
    for (int i = gid; i < NB; i += stride) gcur[i] = i * CAPB;
}

// ======================= CSR build: block multisplit + atomic bucket reservation =======================

__global__ __launch_bounds__(256) void k_scatter_srt(const int* __restrict__ ei,
                                                     int* __restrict__ gcur,
                                                     unsigned* __restrict__ bins, int e) {
    __shared__ unsigned sbuf[EPB];                 // 25 KB staging
    __shared__ int lh[NB], lcur[NB], gdst[NB];
    __shared__ int sA[NB], sBf[NB];
    int b = (int)blockIdx.x, t = (int)threadIdx.x;
    int i0 = b * EPB, i1 = i0 + EPB; if (i1 > e) i1 = e;

    for (int k = t; k < NB; k += 256) lh[k] = 0;
    __syncthreads();
    for (int i = i0 + t * 4; i + 3 < i1; i += 1024) {
        int4 d4 = *(const int4*)(ei + e + i);
        if ((unsigned)d4.x < (unsigned)N_NODES) atomicAdd(&lh[d4.x >> BSH], 1);
        if ((unsigned)d4.y < (unsigned)N_NODES) atomicAdd(&lh[d4.y >> BSH], 1);
        if ((unsigned)d4.z < (unsigned)N_NODES) atomicAdd(&lh[d4.z >> BSH], 1);
        if ((unsigned)d4.w < (unsigned)N_NODES) atomicAdd(&lh[d4.w >> BSH], 1);
    }
    __syncthreads();

    // local inclusive scan over NB buckets (LDS staging offsets)
    int* cur = sA; int* nxt = sBf;
    for (int k = t; k < NB; k += 256) cur[k] = lh[k];
    __syncthreads();
    for (int off = 1; off < NB; off <<= 1) {
        for (int k = t; k < NB; k += 256) nxt[k] = cur[k] + (k >= off ? cur[k - off] : 0);
        __syncthreads();
        int* tmp = cur; cur = nxt; nxt = tmp;
    }
    // reserve global ranges: one atomic per (block, bucket)
    for (int k = t; k < NB; k += 256) {
        lcur[k] = cur[k] - lh[k];
        gdst[k] = lh[k] ? atomicAdd(&gcur[k], lh[k]) : 0;
    }
    __syncthreads();

    // rank + stage into LDS (bucket-sorted within tile)
    for (int i = i0 + t * 4; i + 3 < i1; i += 1024) {
        int4 s4 = *(const int4*)(ei + i);
        int4 d4 = *(const int4*)(ei + e + i);
        int ss[4] = {s4.x, s4.y, s4.z, s4.w};
        int dd[4] = {d4.x, d4.y, d4.z, d4.w};
#pragma unroll
        for (int j = 0; j < 4; ++j) {
            int s = ss[j], d = dd[j];
            if ((unsigned)s >= (unsigned)N_NODES || (unsigned)d >= (unsigned)N_NODES) continue;
            int k = d >> BSH;
            int p = atomicAdd(&lcur[k], 1);
            sbuf[p] = ((unsigned)(d & 255) << 17) | (unsigned)s;
        }
    }
    __syncthreads();

    // contiguous copies into reserved ranges
    int wv = t >> 6, ln = t & 63;
    for (int k = wv; k < NB; k += 4) {
        int cnt = lh[k];
        int src0 = lcur[k] - cnt;
        int dst0 = gdst[k];
        for (int j = ln; j < cnt; j += 64) bins[dst0 + j] = sbuf[src0 + j];
    }
}

__global__ __launch_bounds__(256) void k_bucket(const unsigned* __restrict__ bins,
                                                const int* __restrict__ gcur,
                                                int* __restrict__ rpb, int* __restrict__ rpe,
                                                float* __restrict__ dinv,
                                                int* __restrict__ col, int n) {
    int b = (int)blockIdx.x;
    int t = (int)threadIdx.x;
    int base = b * CAPB;
    int len = gcur[b] - base;
    int nv = len & ~3;
    __shared__ int lcnt[256], lsc[256], lcur[256];
    lcnt[t] = 0;
    __syncthreads();
    for (int i = t * 4; i < nv; i += 1024) {
        uint4 v = *(const uint4*)(bins + base + i);
        atomicAdd(&lcnt[v.x >> 17], 1);
        atomicAdd(&lcnt[v.y >> 17], 1);
        atomicAdd(&lcnt[v.z >> 17], 1);
        atomicAdd(&lcnt[v.w >> 17], 1);
    }
    if (nv + t < len) atomicAdd(&lcnt[bins[base + nv + t] >> 17], 1);
    __syncthreads();
    int c = lcnt[t];
    lsc[t] = c;
    __syncthreads();
    for (int off = 1; off < 256; off <<= 1) {
        int x = (t >= off) ? lsc[t - off] : 0;
        __syncthreads();
        lsc[t] += x;
        __syncthreads();
    }
    int excl = lsc[t] - c;
    int v = (b << BSH) + t;
    if (v < n) {
        rpb[v] = base + excl;
        rpe[v] = base + excl + c;
        dinv[v] = rsqrtf((float)(c + 1));
    }
    lcur[t] = excl;
    __syncthreads();
    for (int i = t * 4; i < nv; i += 1024) {
        uint4 vv = *(const uint4*)(bins + base + i);
        unsigned es[4] = {vv.x, vv.y, vv.z, vv.w};
#pragma unroll
        for (int j = 0; j < 4; ++j) {
            int p = atomicAdd(&lcur[es[j] >> 17], 1);
            col[base + p] = (int)(es[j] & 0x1FFFFu);
        }
    }
    if (nv + t < len) {
        unsigned ent = bins[base + nv + t];
        int p = atomicAdd(&lcur[ent >> 17], 1);
        col[base + p] = (int)(ent & 0x1FFFFu);
    }
}

// ======================= dense MFMA (f32 input): H = (x @ W) * dinv =======================
template <int K, int OUT>
__global__ __launch_bounds__(256) void k_gemm_mfma(const float* __restrict__ x,
                                                   const unsigned short* __restrict__ wt,
                                                   const float* __restrict__ dinv,
                                                   unsigned short* __restrict__ h, int n) {
    constexpr int BM = 64;
    constexpr int BK = 64;
    constexpr int NT = OUT / 16;
    __shared__ unsigned short xs[BM * BK];
    __shared__ unsigned short wsl[OUT * BK];

    int t = (int)threadIdx.x;
    int w = t >> 6;
    int l = t & 63;
    int m0 = blockIdx.x * BM;

    f32x4 acc[NT];
#pragma unroll
    for (int nt = 0; nt < NT; ++nt) acc[nt] = (f32x4){0.f, 0.f, 0.f, 0.f};

    int r = t >> 2, q = t & 3;
    int node_r = m0 + r; if (node_r >= n) node_r = n - 1;

    for (int kb = 0; kb < K; kb += BK) {
        if (kb) __syncthreads();
        const float* xr = x + (long long)node_r * K + kb;
#pragma unroll
        for (int j = 0; j < 2; ++j) {
            int g = q * 2 + j;
            float4 v0 = *(const float4*)(xr + g * 8);
            float4 v1 = *(const float4*)(xr + g * 8 + 4);
            ushort4 lo, hi;
            lo.x = f2bf(v0.x); lo.y = f2bf(v0.y); lo.z = f2bf(v0.z); lo.w = f2bf(v0.w);
            hi.x = f2bf(v1.x); hi.y = f2bf(v1.y); hi.z = f2bf(v1.z); hi.w = f2bf(v1.w);
            int gp = g ^ (r & 7);
            *(ushort4*)&xs[r * BK + gp * 8] = lo;
            *(ushort4*)&xs[r * BK + gp * 8 + 4] = hi;
        }
        for (int f = t; f < OUT * 8; f += 256) {
            int c = f >> 3, g = f & 7;
            uint4 v = *(const uint4*)(wt + (long long)c * K + kb + g * 8);
            int gp = g ^ (c & 7);
            *(uint4*)&wsl[c * BK + gp * 8] = v;
        }
        __syncthreads();
#pragma unroll
        for (int kk = 0; kk < 2; ++kk) {
            int row = w * 16 + (l & 15);
            int gl = kk * 4 + (l >> 4);
            bf16x8 a = *(const bf16x8*)&xs[row * BK + (gl ^ (row & 7)) * 8];
#pragma unroll
            for (int nt = 0; nt < NT; ++nt) {
                int colb = nt * 16 + (l & 15);
                bf16x8 bb = *(const bf16x8*)&wsl[colb * BK + (gl ^ (colb & 7)) * 8];
                acc[nt] = __builtin_amdgcn_mfma_f32_16x16x32_bf16(a, bb, acc[nt], 0, 0, 0);
            }
        }
    }

#pragma unroll
    for (int rg = 0; rg < 4; ++rg) {
        int node = m0 + w * 16 + (l >> 4) * 4 + rg;
        if (node < n) {
            float di = dinv[node];
#pragma unroll
            for (int nt = 0; nt < NT; ++nt)
                h[(long long)node * OUT + nt * 16 + (l & 15)] = f2bf(acc[nt][rg] * di);
        }
    }
}

// ======================= dense MFMA (bf16 input): H = (A @ W) * dinv =======================
template <int K, int OUT>
__global__ __launch_bounds__(256) void k_gemm_mfma_b16(const unsigned short* __restrict__ x,
                                                       const unsigned short* __restrict__ wt,
                                                       const float* __restrict__ dinv,
                                                       unsigned short* __restrict__ h, int n) {
    constexpr int BM = 64;
    constexpr int NT = OUT / 16;
    constexpr int GR = K / 8;
    constexpr int SM = GR - 1;
    __shared__ unsigned short xs[BM * K];
    __shared__ unsigned short wsl[OUT * K];

    int t = (int)threadIdx.x;
    int w = t >> 6;
    int l = t & 63;
    int m0 = blockIdx.x * BM;

    f32x4 acc[NT];
#pragma unroll
    for (int nt = 0; nt < NT; ++nt) acc[nt] = (f32x4){0.f, 0.f, 0.f, 0.f};

    constexpr int PER = (BM * GR) / 256;
#pragma unroll
    for (int f = 0; f < PER; ++f) {
        int flat = f * 256 + t;
        int row = flat / GR;
        int g = flat % GR;
        int node = m0 + row; if (node >= n) node = n - 1;
        uint4 v = *(const uint4*)(x + (long long)node * K + g * 8);
        *(uint4*)&xs[row * K + (g ^ (row & SM)) * 8] = v;
    }
    for (int f = t; f < OUT * GR; f += 256) {
        int c = f / GR, g = f % GR;
        uint4 v = *(const uint4*)(wt + (long long)c * K + g * 8);
        *(uint4*)&wsl[c * K + (g ^ (c & SM)) * 8] = v;
    }
    __syncthreads();

#pragma unroll
    for (int kk = 0; kk < K / 32; ++kk) {
        int row = w * 16 + (l & 15);
        int gl = kk * 4 + (l >> 4);
        bf16x8 a = *(const bf16x8*)&xs[row * K + (gl ^ (row & SM)) * 8];
#pragma unroll
        for (int nt = 0; nt < NT; ++nt) {
            int colb = nt * 16 + (l & 15);
            bf16x8 bb = *(const bf16x8*)&wsl[colb * K + (gl ^ (colb & SM)) * 8];
            acc[nt] = __builtin_amdgcn_mfma_f32_16x16x32_bf16(a, bb, acc[nt], 0, 0, 0);
        }
    }

#pragma unroll
    for (int rg = 0; rg < 4; ++rg) {
        int node = m0 + w * 16 + (l >> 4) * 4 + rg;
        if (node < n) {
            float di = dinv[node];
#pragma unroll
            for (int nt = 0; nt < NT; ++nt)
                h[(long long)node * OUT + nt * 16 + (l & 15)] = f2bf(acc[nt][rg] * di);
        }
    }
}

// per-wave gemm for the tiny final layer (K=16, OUT=4), bf16 input
template <int K, int OUT, int NPW>
__global__ void k_gemm(const unsigned short* __restrict__ x, const float* __restrict__ W,
                       const float* __restrict__ dinv, unsigned short* __restrict__ h, int n) {
    constexpr int NS = 64 / OUT;
    constexpr int KC = (K < 64 * NS) ? K : 64 * NS;
    constexpr int JW = KC / NS;

    int tid = blockIdx.x * blockDim.x + threadIdx.x;
    int wid = __builtin_amdgcn_readfirstlane(tid >> 6);
    int lane = (int)threadIdx.x & 63;
    int o = lane % OUT;
    int s = lane / OUT;

    long long base = (long long)wid * NPW;
    if (base >= n) return;

    float acc[NPW];
#pragma unroll
    for (int m = 0; m < NPW; ++m) acc[m] = 0.0f;

    float w[JW];
    for (int kb = 0; kb < K; kb += KC) {
        const float* Wp = W + (long long)kb * OUT;
#pragma unroll
        for (int j = 0; j < JW; ++j) w[j] = Wp[j * 64 + lane];
#pragma unroll
        for (int m = 0; m < NPW; ++m) {
            const unsigned short* xr = x + (base + m) * K + kb;
#pragma unroll
            for (int j = 0; j < JW; ++j)
                acc[m] = fmaf(bf2f(xr[j * NS + s]), w[j], acc[m]);
        }
    }

#pragma unroll
    for (int m = 0; m < NPW; ++m)
#pragma unroll
        for (int off = OUT; off < 64; off <<= 1)
            acc[m] += __shfl_xor(acc[m], off, 64);

    if (s == 0) {
#pragma unroll
        for (int m = 0; m < NPW; ++m) {
            long long v = base + m;
            if (v < n) h[v * OUT + o] = f2bf(acc[m] * dinv[v]);
        }
    }
}

// ======================= sparse aggregate (bf16 gather, f32 acc) =======================
// D >= 16: bf16 relu output.
template <int D>
__global__ void k_aggregate(const unsigned short* __restrict__ h, const int* __restrict__ rpb,
                            const int* __restrict__ rpe, const int* __restrict__ col,
                            const float* __restrict__ dinv, const float* __restrict__ b,
                            unsigned short* __restrict__ out, int n) {
    constexpr int LPR = D / 8;
    constexpr int EG = 64 / LPR;
    int v = (int)((blockIdx.x * blockDim.x + threadIdx.x) >> 6);
    if (v >= n) return;
    int lane = (int)threadIdx.x & 63;
    int eg = lane / LPR;
    int o8 = lane % LPR;
    const unsigned short* hq = h + o8 * 8;
    int beg = rpb[v], end = rpe[v];

    float acc[8];
#pragma unroll
    for (int j = 0; j < 8; ++j) acc[j] = 0.0f;

    int i = beg + eg;
    for (; i + 3 * EG < end; i += 4 * EG) {
        int s0 = col[i], s1 = col[i + EG], s2 = col[i + 2 * EG], s3 = col[i + 3 * EG];
        uint4 h0 = *(const uint4*)(hq + (long long)s0 * D);
        uint4 h1 = *(const uint4*)(hq + (long long)s1 * D);
        uint4 h2 = *(const uint4*)(hq + (long long)s2 * D);
        uint4 h3 = *(const uint4*)(hq + (long long)s3 * D);
        acc[0] += bfp_lo(h0.x) + bfp_lo(h1.x) + bfp_lo(h2.x) + bfp_lo(h3.x);
        acc[1] += bfp_hi(h0.x) + bfp_hi(h1.x) + bfp_hi(h2.x) + bfp_hi(h3.x);
        acc[2] += bfp_lo(h0.y) + bfp_lo(h1.y) + bfp_lo(h2.y) + bfp_lo(h3.y);
        acc[3] += bfp_hi(h0.y) + bfp_hi(h1.y) + bfp_hi(h2.y) + bfp_hi(h3.y);
        acc[4] += bfp_lo(h0.z) + bfp_lo(h1.z) + bfp_lo(h2.z) + bfp_lo(h3.z);
        acc[5] += bfp_hi(h0.z) + bfp_hi(h1.z) + bfp_hi(h2.z) + bfp_hi(h3.z);
        acc[6] += bfp_lo(h0.w) + bfp_lo(h1.w) + bfp_lo(h2.w) + bfp_lo(h3.w);
        acc[7] += bfp_hi(h0.w) + bfp_hi(h1.w) + bfp_hi(h2.w) + bfp_hi(h3.w);
    }
    for (; i + EG < end; i += 2 * EG) {
        int s0 = col[i], s1 = col[i + EG];
        uint4 h0 = *(const uint4*)(hq + (long long)s0 * D);
        uint4 h1 = *(const uint4*)(hq + (long long)s1 * D);
        acc[0] += bfp_lo(h0.x) + bfp_lo(h1.x);
        acc[1] += bfp_hi(h0.x) + bfp_hi(h1.x);
        acc[2] += bfp_lo(h0.y) + bfp_lo(h1.y);
        acc[3] += bfp_hi(h0.y) + bfp_hi(h1.y);
        acc[4] += bfp_lo(h0.z) + bfp_lo(h1.z);
        acc[5] += bfp_hi(h0.z) + bfp_hi(h1.z);
        acc[6] += bfp_lo(h0.w) + bfp_lo(h1.w);
        acc[7] += bfp_hi(h0.w) + bfp_hi(h1.w);
    }
    for (; i < end; i += EG) {
        int s = col[i];
        uint4 hv = *(const uint4*)(hq + (long long)s * D);
        acc[0] += bfp_lo(hv.x); acc[1] += bfp_hi(hv.x);
        acc[2] += bfp_lo(hv.y); acc[3] += bfp_hi(hv.y);
        acc[4] += bfp_lo(hv.z); acc[5] += bfp_hi(hv.z);
        acc[6] += bfp_lo(hv.w); acc[7] += bfp_hi(hv.w);
    }

#pragma unroll
    for (int off = LPR; off < 64; off <<= 1)
#pragma unroll
        for (int j = 0; j < 8; ++j) acc[j] += __shfl_xor(acc[j], off, 64);

    if (lane < LPR) {
        uint4 sv = *(const uint4*)(h + (long long)v * D + o8 * 8);
        float self[8] = {bfp_lo(sv.x), bfp_hi(sv.x), bfp_lo(sv.y), bfp_hi(sv.y),
                         bfp_lo(sv.z), bfp_hi(sv.z), bfp_lo(sv.w), bfp_hi(sv.w)};
        float4 b0 = *(const float4*)(b + o8 * 8);
        float4 b1 = *(const float4*)(b + o8 * 8 + 4);
        float bb[8] = {b0.x, b0.y, b0.z, b0.w, b1.x, b1.y, b1.z, b1.w};
        float di = dinv[v];
        ushort4 t0, t1;
        t0.x = f2bf(fmaxf(di * (acc[0] + self[0]) + bb[0], 0.f));
        t0.y = f2bf(fmaxf(di * (acc[1] + self[1]) + bb[1], 0.f));
        t0.z = f2bf(fmaxf(di * (acc[2] + self[2]) + bb[2], 0.f));
        t0.w = f2bf(fmaxf(di * (acc[3] + self[3]) + bb[3], 0.f));
        t1.x = f2bf(fmaxf(di * (acc[4] + self[4]) + bb[4], 0.f));
        t1.y = f2bf(fmaxf(di * (acc[5] + self[5]) + bb[5], 0.f));
        t1.z = f2bf(fmaxf(di * (acc[6] + self[6]) + bb[6], 0.f));
        t1.w = f2bf(fmaxf(di * (acc[7] + self[7]) + bb[7], 0.f));
        unsigned short* op = out + (long long)v * D + o8 * 8;
        *(ushort4*)op = t0;
        *(ushort4*)(op + 4) = t1;
    }
}

// ======================= final aggregate (D=4, 4 nodes/wave, log_softmax -> f32) =======================
__global__ void k_aggregate4(const unsigned short* __restrict__ h, const int* __restrict__ rpb,
                             const int* __restrict__ rpe, const int* __restrict__ col,
                             const float* __restrict__ dinv, const float* __restrict__ b,
                             float* __restrict__ out, int n) {
    int lane = (int)threadIdx.x & 63;
    int wave = (int)((blockIdx.x * blockDim.x + threadIdx.x) >> 6);
    int v = wave * 4 + (lane >> 4);   // 4 nodes per wave, 16 lanes each
    if (v >= n) return;
    int sl = lane & 15;
    int beg = rpb[v], end = rpe[v];

    float4 acc = make_float4(0.f, 0.f, 0.f, 0.f);
    for (int i = beg + sl; i < end; i += 16) {
        int s = col[i];
        ushort4 hv = *(const ushort4*)(h + (long long)s * 4);
        acc.x += bf2f(hv.x); acc.y += bf2f(hv.y);
        acc.z += bf2f(hv.z); acc.w += bf2f(hv.w);
    }
#pragma unroll
    for (int off = 1; off < 16; off <<= 1) {
        acc.x += __shfl_xor(acc.x, off, 64);
        acc.y += __shfl_xor(acc.y, off, 64);
        acc.z += __shfl_xor(acc.z, off, 64);
        acc.w += __shfl_xor(acc.w, off, 64);
    }
    if (sl == 0) {
        ushort4 sv = *(const ushort4*)(h + (long long)v * 4);
        float4 bb = *(const float4*)b;
        float di = dinv[v];
        float x0 = di * (acc.x + bf2f(sv.x)) + bb.x;
        float x1 = di * (acc.y + bf2f(sv.y)) + bb.y;
        float x2 = di * (acc.z + bf2f(sv.z)) + bb.z;
        float x3 = di * (acc.w + bf2f(sv.w)) + bb.w;
        float m = fmaxf(fmaxf(x0, x1), fmaxf(x2, x3));
        float s0 = __expf(x0 - m) + __expf(x1 - m) + __expf(x2 - m) + __expf(x3 - m);
        float ls = m + __logf(s0);
        *(float4*)(out + (long long)v * 4) =
            make_float4(x0 - ls, x1 - ls, x2 - ls, x3 - ls);
    }
}

// ======================= launch =======================

extern "C" void kernel_launch(void* const* d_in, const int* in_sizes, int n_in,
                              void* d_out, int out_size, void* d_ws, size_t ws_size,
                              hipStream_t stream) {
    const float* x = (const float*)d_in[0];
    const int* ei = (const int*)d_in[1];  // int32 [2, E]
    const float* W1 = (const float*)d_in[2];
    const float* b1 = (const float*)d_in[3];
    const float* W2 = (const float*)d_in[4];
    const float* b2 = (const float*)d_in[5];
    const float* W3 = (const float*)d_in[6];
    const float* b3 = (const float*)d_in[7];
    const float* W4 = (const float*)d_in[8];
    const float* b4 = (const float*)d_in[9];
    float* out = (float*)d_out;

    const int n = N_NODES;
    const int e = N_EDGES;
    const int B = 256;

    char* ws = (char*)d_ws;
    size_t off = 0;
    auto alloc = [&](size_t bytes) {
        void* p = ws + off;
        off += (bytes + 255) & ~size_t(255);
        return p;
    };
    float* dinv = (float*)alloc((size_t)n * 4);
    int* rpb = (int*)alloc((size_t)n * 4);
    int* rpe = (int*)alloc((size_t)n * 4);
    int* gcur = (int*)alloc((size_t)NB * 4);
    unsigned* bins = (unsigned*)alloc((size_t)NB * CAPB * 4);   // 14.4 MB
    int* col = (int*)alloc((size_t)NB * CAPB * 4);              // 14.4 MB
    unsigned short* H = (unsigned short*)alloc((size_t)n * 64 * 2);   // bf16
    unsigned short* A = (unsigned short*)alloc((size_t)n * 64 * 2);   // bf16 activations
    unsigned short* wt1 = (unsigned short*)alloc((size_t)64 * 256 * 2);
    unsigned short* wt2 = (unsigned short*)alloc((size_t)32 * 64 * 2);
    unsigned short* wt3 = (unsigned short*)alloc((size_t)16 * 32 * 2);

    // ---- prep (W^T bf16, bucket cursors) + CSR build ----
    k_prep<<<18, B, 0, stream>>>(W1, W2, W3, wt1, wt2, wt3, gcur);
    k_scatter_srt<<<G_SRT, B, 0, stream>>>(ei, gcur, bins, e);
    k_bucket<<<NB, B, 0, stream>>>(bins, gcur, rpb, rpe, dinv, col, n);

    const int gblk = (n + 63) / 64;   // BM=64 blocks
    const int ablk = (n + 3) / 4;     // aggregate blocks (4 waves / block)
    const int a4blk = (n + 15) / 16;  // final aggregate (16 nodes / block)

    // ---- layer 1: 256 -> 64 (MFMA f32-in), relu -> A bf16 ----
    k_gemm_mfma<256, 64><<<gblk, B, 0, stream>>>(x, wt1, dinv, H, n);
    k_aggregate<64><<<ablk, B, 0, stream>>>(H, rpb, rpe, col, dinv, b1, A, n);

    // ---- layer 2: 64 -> 32 (MFMA bf16-in), relu ----
    k_gemm_mfma_b16<64, 32><<<gblk, B, 0, stream>>>(A, wt2, dinv, H, n);
    k_aggregate<32><<<ablk, B, 0, stream>>>(H, rpb, rpe, col, dinv, b2, A, n);

    // ---- layer 3: 32 -> 16 (MFMA bf16-in), relu ----
    k_gemm_mfma_b16<32, 16><<<gblk, B, 0, stream>>>(A, wt3, dinv, H, n);
    k_aggregate<16><<<ablk, B, 0, stream>>>(H, rpb, rpe, col, dinv, b3, A, n);

    // ---- layer 4: 16 -> 4, log_softmax ----
    {
        constexpr int NPW = 16;
        const int g4 = ((n + NPW - 1) / NPW + 3) / 4;
        k_gemm<16, 4, NPW><<<g4, B, 0, stream>>>(A, W4, dinv, H, n);
        k_aggregate4<<<a4blk, B, 0, stream>>>(H, rpb, rpe, col, dinv, b4, out, n);
    }
}